// Round 5
// baseline (20455.223 us; speedup 1.0000x reference)
//
#include <hip/hip_runtime.h>
#include <cstddef>

#define BB 64
#define LL 512
#define II 256
#define HH 512

typedef _Float16 f16;
typedef _Float16 f16x8 __attribute__((ext_vector_type(8)));
typedef float f32x4 __attribute__((ext_vector_type(4)));
typedef unsigned u32x2 __attribute__((ext_vector_type(2)));

// ws layout in f16 units (unchanged from R4 except flag count):
//   W0F  @ 0        : [j=16][kb=16][tn=2][L=64][e=8]  = 262144
//   W1F  @ 262144   : same
//   WGF  @ 524288   : [j=16][kb=24][tt=6][L=64][e=8]  = 1179648
//   YBUF @ 1703936  : [c=4][p=2][m=16][col=512]        = 65536   (m-major)
//   FLAGS @ byte 3538944 : 4 clusters x 32 slots x 16B = 2048 B
#define W0F_H 0
#define W1F_H 262144
#define WGF_H 524288
#define YBUF_H 1703936
#define FLAGS_B 3538944
#define N0 262144
#define N1 262144
#define N2 1179648
#define N3 32768
#define N4 512
#define PREP_TOTAL (N0 + N1 + N2 + N3 + N4)

__global__ void prep_kernel(const float* __restrict__ dw0, const float* __restrict__ dw1,
                            const float* __restrict__ w_ih, const float* __restrict__ w_hh,
                            const float* __restrict__ h0, f16* __restrict__ wsh) {
    int idx = blockIdx.x * 256 + threadIdx.x;
    if (idx >= PREP_TOTAL) return;
    if (idx < N0 + N1) {
        const float* src = (idx < N0) ? dw0 : dw1;
        int r = (idx < N0) ? idx : idx - N0;
        int e = r & 7, L = (r >> 3) & 63, tn = (r >> 9) & 1, kb = (r >> 10) & 15, j = r >> 14;
        int n = j * 32 + tn * 16 + (L & 15);
        int k = kb * 32 + (L >> 4) * 8 + e;
        wsh[idx] = (f16)src[n * 512 + k];
        return;
    }
    idx -= (N0 + N1);
    if (idx < N2) {
        int e = idx & 7, L = (idx >> 3) & 63;
        int rest = idx >> 9;
        int tt = rest % 6, r2 = rest / 6;
        int kb = r2 % 24, j = r2 / 24;
        int g = tt >> 1, tn = tt & 1;
        int n = g * 512 + j * 32 + tn * 16 + (L & 15);
        int kc = kb * 32 + (L >> 4) * 8 + e;
        float v = (kc < 256) ? w_ih[n * 256 + kc] : w_hh[n * 512 + (kc - 256)];
        wsh[WGF_H + idx] = (f16)v;
        return;
    }
    idx -= N2;
    if (idx < N3) {
        int col = idx & 511, m = (idx >> 9) & 15, c = idx >> 13;
        wsh[YBUF_H + (size_t)c * 16384 + m * 512 + col] = (f16)h0[col];
        return;
    }
    idx -= N3;
    ((unsigned*)((char*)wsh + FLAGS_B))[idx] = 0u;
}

// sc0 sc1 = device-coherent at the Infinity Cache; no buffer_inv/wbl2 needed.
__device__ __forceinline__ void st_u32_sc(unsigned* p, unsigned v) {
    asm volatile("global_store_dword %0, %1, off sc0 sc1" :: "v"(p), "v"(v) : "memory");
}
__device__ __forceinline__ unsigned ld_u32_sc(const unsigned* p) {
    unsigned v;
    asm volatile("global_load_dword %0, %1, off sc0 sc1\n\ts_waitcnt vmcnt(0)"
                 : "=v"(v) : "v"(p) : "memory");
    return v;
}
// 4 f16 -> one contiguous 8B device-coherent store
__device__ __forceinline__ void st4_sc(f16* p, float v0, float v1, float v2, float v3) {
    union { f16 h[4]; u32x2 u; } pk;
    pk.h[0] = (f16)v0; pk.h[1] = (f16)v1; pk.h[2] = (f16)v2; pk.h[3] = (f16)v3;
    asm volatile("global_store_dwordx2 %0, %1, off sc0 sc1" :: "v"(p), "v"(pk.u) : "memory");
}

// 16 B-fragments (full K=512 row of one batch-row m) in one burst, single drain
__device__ __forceinline__ void ld16_sc(const f16* p, f16x8 b[16]) {
    f32x4 t0,t1,t2,t3,t4,t5,t6,t7,t8,t9,t10,t11,t12,t13,t14,t15;
    asm volatile(
        "global_load_dwordx4 %0, %16, off sc0 sc1\n\t"
        "global_load_dwordx4 %1, %16, off offset:64 sc0 sc1\n\t"
        "global_load_dwordx4 %2, %16, off offset:128 sc0 sc1\n\t"
        "global_load_dwordx4 %3, %16, off offset:192 sc0 sc1\n\t"
        "global_load_dwordx4 %4, %16, off offset:256 sc0 sc1\n\t"
        "global_load_dwordx4 %5, %16, off offset:320 sc0 sc1\n\t"
        "global_load_dwordx4 %6, %16, off offset:384 sc0 sc1\n\t"
        "global_load_dwordx4 %7, %16, off offset:448 sc0 sc1\n\t"
        "global_load_dwordx4 %8, %16, off offset:512 sc0 sc1\n\t"
        "global_load_dwordx4 %9, %16, off offset:576 sc0 sc1\n\t"
        "global_load_dwordx4 %10, %16, off offset:640 sc0 sc1\n\t"
        "global_load_dwordx4 %11, %16, off offset:704 sc0 sc1\n\t"
        "global_load_dwordx4 %12, %16, off offset:768 sc0 sc1\n\t"
        "global_load_dwordx4 %13, %16, off offset:832 sc0 sc1\n\t"
        "global_load_dwordx4 %14, %16, off offset:896 sc0 sc1\n\t"
        "global_load_dwordx4 %15, %16, off offset:960 sc0 sc1\n\t"
        "s_waitcnt vmcnt(0)"
        : "=&v"(t0), "=&v"(t1), "=&v"(t2), "=&v"(t3), "=&v"(t4), "=&v"(t5),
          "=&v"(t6), "=&v"(t7), "=&v"(t8), "=&v"(t9), "=&v"(t10), "=&v"(t11),
          "=&v"(t12), "=&v"(t13), "=&v"(t14), "=&v"(t15)
        : "v"(p) : "memory");
    union { f32x4 f; f16x8 h; } u;
    u.f = t0;  b[0] = u.h;  u.f = t1;  b[1] = u.h;  u.f = t2;  b[2] = u.h;
    u.f = t3;  b[3] = u.h;  u.f = t4;  b[4] = u.h;  u.f = t5;  b[5] = u.h;
    u.f = t6;  b[6] = u.h;  u.f = t7;  b[7] = u.h;  u.f = t8;  b[8] = u.h;
    u.f = t9;  b[9] = u.h;  u.f = t10; b[10] = u.h; u.f = t11; b[11] = u.h;
    u.f = t12; b[12] = u.h; u.f = t13; b[13] = u.h; u.f = t14; b[14] = u.h;
    u.f = t15; b[15] = u.h;
}

// wave-level poll: lane l watches slot l&31; wave proceeds when all 32 slots >= target
__device__ __forceinline__ void poll32(const unsigned* slots, int L, unsigned target) {
    const unsigned* p = slots + (L & 31) * 4;
    while (ld_u32_sc(p) < target) __builtin_amdgcn_s_sleep(1);
}

__launch_bounds__(512, 1)
__global__ void odegru_kernel(const float* __restrict__ x, const float* __restrict__ tds,
                              const float* __restrict__ b_ih, const float* __restrict__ b_hh,
                              const float* __restrict__ db0, const float* __restrict__ db1,
                              const float* __restrict__ h0, const int* __restrict__ seq_lens,
                              f16* __restrict__ wsh, float* __restrict__ out) {
    __shared__ f16 W0s[16384];
    __shared__ f16 W1s[16384];
    __shared__ f16 Xbuf[16 * 264];
    __shared__ float Gate[8 * 64 * 4];

    const int tid = threadIdx.x;
    const int w = tid >> 6;
    const int L = tid & 63;
    const int L15 = L & 15;   // = m (batch row within cluster)
    const int Lq = L >> 4;
    const int bid = blockIdx.x;
    const int c = bid & 3;    // fixed cluster (no placement assumptions -> no hang)
    const int j = bid >> 2;   // N-slice owner (0..15)
    const int b0 = c * 16;
    const int m = L15;

    unsigned* slots = (unsigned*)((char*)wsh + FLAGS_B + (size_t)c * 512);
    f16* yb0 = wsh + YBUF_H + (size_t)c * 16384;  // 2 ping-pong buffers of 8192 f16

    // weights -> LDS (frag-linear; A-operand layout == old B-operand layout)
    {
        const f16* w0g = wsh + W0F_H + (size_t)j * 16384;
        const f16* w1g = wsh + W1F_H + (size_t)j * 16384;
        for (int i = tid; i < 2048; i += 512) {
            *(f16x8*)&W0s[i * 8] = *(const f16x8*)&w0g[i * 8];
            *(f16x8*)&W1s[i * 8] = *(const f16x8*)&w1g[i * 8];
        }
    }
    // GRU fused weights -> registers (waves 2..7, tt = w-2)
    f16x8 wgr[24];
    if (w >= 2) {
        const int tt = w - 2;
        const f16* wgg = wsh + WGF_H;
#pragma unroll
        for (int kb = 0; kb < 24; ++kb)
            wgr[kb] = *(const f16x8*)&wgg[((((size_t)j * 24 + kb) * 6 + tt) * 64 + L) * 8];
    }

    // per-lane state for waves 0,1: lane owns cols n0..n0+3 at batch row m
    const int tn = w & 1;
    const int n0 = j * 32 + tn * 16 + Lq * 4;
    f32x4 h = {0,0,0,0}, k1 = h, k2 = h, k3 = h, hode = h;
    f32x4 d0b = h, d1b = h, bR = h, bZ = h, bN = h, bHR = h, bHZ = h, bHN = h;
    int slW = 0;
    if (w < 2) {
        h   = *(const f32x4*)&h0[n0];
        d0b = *(const f32x4*)&db0[n0];
        d1b = *(const f32x4*)&db1[n0];
        bR  = *(const f32x4*)&b_ih[n0];
        bZ  = *(const f32x4*)&b_ih[512 + n0];
        bN  = *(const f32x4*)&b_ih[1024 + n0];
        bHR = *(const f32x4*)&b_hh[n0];
        bHZ = *(const f32x4*)&b_hh[512 + n0];
        bHN = *(const f32x4*)&b_hh[1024 + n0];
        slW = seq_lens[b0 + m];
    }
    // x-staging assignment (threads 128..383)
    const int sidx = tid - 128;
    int sl2 = 0;
    if (w >= 2 && sidx < 256) sl2 = seq_lens[b0 + (sidx >> 4)];

    // stage x for t=0
    if (w >= 2 && sidx < 256) {
        int m2 = sidx >> 4, o = sidx & 15;
        const float* xp = x + ((size_t)(b0 + m2) * LL + 0) * II + o * 16;
        f16x8 v0, v1;
        if (0 < sl2) {
            f32x4 xa = *(const f32x4*)xp, xb = *(const f32x4*)(xp + 4);
            f32x4 xc = *(const f32x4*)(xp + 8), xd = *(const f32x4*)(xp + 12);
#pragma unroll
            for (int e = 0; e < 4; ++e) {
                v0[e] = (f16)xa[e]; v0[4 + e] = (f16)xb[e];
                v1[e] = (f16)xc[e]; v1[4 + e] = (f16)xd[e];
            }
        } else {
#pragma unroll
            for (int e = 0; e < 8; ++e) { v0[e] = (f16)0.f; v1[e] = (f16)0.f; }
        }
        *(f16x8*)&Xbuf[m2 * 264 + o * 16] = v0;
        *(f16x8*)&Xbuf[m2 * 264 + o * 16 + 8] = v1;
    }
    __syncthreads();

    for (int t = 0; t < LL; ++t) {
        const int qb = t * 9;
        if (w < 2) {
            // ---------------- 8 barrier-free ODE passes (waves 0,1 only) --------------
            const float td = (t < slW) ? tds[(size_t)(b0 + m) * LL + t] : 0.f;
#pragma unroll 1
            for (int s = 0; s < 4; ++s) {
                // W0 pass
                {
                    const int q = qb + 2 * s;
                    const f16* rbuf = yb0 + (q & 1) * 8192;
                    f16* wbuf = yb0 + ((q & 1) ^ 1) * 8192;
                    poll32(slots, L, (unsigned)q);
                    f16x8 bfr[16];
                    ld16_sc(rbuf + m * 512 + Lq * 8, bfr);
                    f32x4 a0 = {0,0,0,0}, a1 = a0, a2 = a0, a3 = a0;
#pragma unroll
                    for (int kb = 0; kb < 16; kb += 4) {
                        a0 = __builtin_amdgcn_mfma_f32_16x16x32_f16(
                            *(const f16x8*)&W0s[((kb + 0) * 2 + tn) * 512 + L * 8], bfr[kb + 0], a0, 0, 0, 0);
                        a1 = __builtin_amdgcn_mfma_f32_16x16x32_f16(
                            *(const f16x8*)&W0s[((kb + 1) * 2 + tn) * 512 + L * 8], bfr[kb + 1], a1, 0, 0, 0);
                        a2 = __builtin_amdgcn_mfma_f32_16x16x32_f16(
                            *(const f16x8*)&W0s[((kb + 2) * 2 + tn) * 512 + L * 8], bfr[kb + 2], a2, 0, 0, 0);
                        a3 = __builtin_amdgcn_mfma_f32_16x16x32_f16(
                            *(const f16x8*)&W0s[((kb + 3) * 2 + tn) * 512 + L * 8], bfr[kb + 3], a3, 0, 0, 0);
                    }
                    f32x4 acc = (a0 + a1) + (a2 + a3);
                    float u0 = tanhf(acc[0] + d0b[0]), u1 = tanhf(acc[1] + d0b[1]);
                    float u2 = tanhf(acc[2] + d0b[2]), u3 = tanhf(acc[3] + d0b[3]);
                    st4_sc(wbuf + m * 512 + n0, u0, u1, u2, u3);
                    asm volatile("s_waitcnt vmcnt(0)" ::: "memory");
                    if (L == 0) st_u32_sc(slots + (j * 2 + tn) * 4, (unsigned)(q + 1));
                }
                // W1 pass
                {
                    const int q = qb + 2 * s + 1;
                    const f16* rbuf = yb0 + (q & 1) * 8192;
                    f16* wbuf = yb0 + ((q & 1) ^ 1) * 8192;
                    poll32(slots, L, (unsigned)q);
                    f16x8 bfr[16];
                    ld16_sc(rbuf + m * 512 + Lq * 8, bfr);
                    f32x4 a0 = {0,0,0,0}, a1 = a0, a2 = a0, a3 = a0;
#pragma unroll
                    for (int kb = 0; kb < 16; kb += 4) {
                        a0 = __builtin_amdgcn_mfma_f32_16x16x32_f16(
                            *(const f16x8*)&W1s[((kb + 0) * 2 + tn) * 512 + L * 8], bfr[kb + 0], a0, 0, 0, 0);
                        a1 = __builtin_amdgcn_mfma_f32_16x16x32_f16(
                            *(const f16x8*)&W1s[((kb + 1) * 2 + tn) * 512 + L * 8], bfr[kb + 1], a1, 0, 0, 0);
                        a2 = __builtin_amdgcn_mfma_f32_16x16x32_f16(
                            *(const f16x8*)&W1s[((kb + 2) * 2 + tn) * 512 + L * 8], bfr[kb + 2], a2, 0, 0, 0);
                        a3 = __builtin_amdgcn_mfma_f32_16x16x32_f16(
                            *(const f16x8*)&W1s[((kb + 3) * 2 + tn) * 512 + L * 8], bfr[kb + 3], a3, 0, 0, 0);
                    }
                    f32x4 acc = (a0 + a1) + (a2 + a3);
                    f32x4 yv;
#pragma unroll
                    for (int r = 0; r < 4; ++r) {
                        float kv = tanhf(acc[r] + d1b[r]) * td;
                        if (s == 0)      { k1[r] = kv; yv[r] = h[r] + kv * (1.f / 3.f); }
                        else if (s == 1) { k2[r] = kv; yv[r] = h[r] + kv - k1[r] * (1.f / 3.f); }
                        else if (s == 2) { k3[r] = kv; yv[r] = h[r] + k1[r] - k2[r] + kv; }
                        else { hode[r] = h[r] + (k1[r] + 3.f * (k2[r] + k3[r]) + kv) * 0.125f;
                               yv[r] = hode[r]; }
                    }
                    st4_sc(wbuf + m * 512 + n0, yv[0], yv[1], yv[2], yv[3]);
                    asm volatile("s_waitcnt vmcnt(0)" ::: "memory");
                    if (L == 0) st_u32_sc(slots + (j * 2 + tn) * 4, (unsigned)(q + 1));
                }
            }
        } else {
            // ---------------- GRU gate matmuls (waves 2..7) ---------------------------
            const int tt = w - 2;
            f32x4 aA = {0,0,0,0};
#pragma unroll
            for (int kb = 0; kb < 8; ++kb) {
                f16x8 b = *(const f16x8*)&Xbuf[L15 * 264 + kb * 32 + Lq * 8];
                aA = __builtin_amdgcn_mfma_f32_16x16x32_f16(wgr[kb], b, aA, 0, 0, 0);
            }
            poll32(slots, L, (unsigned)(qb + 8));  // wait for hode
            const f16* rbuf = yb0 + ((qb + 8) & 1) * 8192;
            f16x8 bfr[16];
            ld16_sc(rbuf + L15 * 512 + Lq * 8, bfr);
            f32x4 aB = {0,0,0,0};
#pragma unroll
            for (int kb = 0; kb < 16; ++kb)
                aB = __builtin_amdgcn_mfma_f32_16x16x32_f16(wgr[8 + kb], bfr[kb], aB, 0, 0, 0);
            if (tt < 4) {
#pragma unroll
                for (int r = 0; r < 4; ++r) Gate[tt * 256 + L * 4 + r] = aA[r] + aB[r];
            } else {
#pragma unroll
                for (int r = 0; r < 4; ++r) {
                    Gate[tt * 256 + L * 4 + r] = aA[r];
                    Gate[(tt + 2) * 256 + L * 4 + r] = aB[r];
                }
            }
        }
        __syncthreads();  // barrier 1: Gate ready

        if (w < 2) {
            // finalize GRU, write out + next hidden state
            f16* wbuf = yb0 + ((qb + 9) & 1) * 8192;
            f32x4 hn;
#pragma unroll
            for (int r = 0; r < 4; ++r) {
                float g0  = Gate[(0 + tn) * 256 + L * 4 + r];
                float g1  = Gate[(2 + tn) * 256 + L * 4 + r];
                float gix = Gate[(4 + tn) * 256 + L * 4 + r];
                float ghn = Gate[(6 + tn) * 256 + L * 4 + r];
                float rg = 1.f / (1.f + __expf(-(g0 + bR[r] + bHR[r])));
                float z  = 1.f / (1.f + __expf(-(g1 + bZ[r] + bHZ[r])));
                float nn = tanhf(gix + bN[r] + rg * (ghn + bHN[r]));
                hn[r] = (1.f - z) * nn + z * hode[r];
                h[r] = hn[r];
            }
            *(f32x4*)&out[((size_t)(b0 + m) * LL + t) * HH + n0] = hn;
            st4_sc(wbuf + m * 512 + n0, hn[0], hn[1], hn[2], hn[3]);
            asm volatile("s_waitcnt vmcnt(0)" ::: "memory");
            if (L == 0) st_u32_sc(slots + (j * 2 + tn) * 4, (unsigned)(qb + 9));
        } else if (sidx < 256 && t + 1 < LL) {
            // stage x for t+1 (overlaps waves 0-1's finalize)
            int m2 = sidx >> 4, o = sidx & 15;
            const float* xp = x + ((size_t)(b0 + m2) * LL + (t + 1)) * II + o * 16;
            f16x8 v0, v1;
            if (t + 1 < sl2) {
                f32x4 xa = *(const f32x4*)xp, xb = *(const f32x4*)(xp + 4);
                f32x4 xc = *(const f32x4*)(xp + 8), xd = *(const f32x4*)(xp + 12);
#pragma unroll
                for (int e = 0; e < 4; ++e) {
                    v0[e] = (f16)xa[e]; v0[4 + e] = (f16)xb[e];
                    v1[e] = (f16)xc[e]; v1[4 + e] = (f16)xd[e];
                }
            } else {
#pragma unroll
                for (int e = 0; e < 8; ++e) { v0[e] = (f16)0.f; v1[e] = (f16)0.f; }
            }
            *(f16x8*)&Xbuf[m2 * 264 + o * 16] = v0;
            *(f16x8*)&Xbuf[m2 * 264 + o * 16 + 8] = v1;
        }
        __syncthreads();  // barrier 2: Xbuf(t+1) staged, Gate free for reuse
    }
}

__global__ void finalize_kernel(const int* __restrict__ seq_lens, float* __restrict__ out) {
    int b = blockIdx.x;
    int n = threadIdx.x;
    int sl = seq_lens[b];
    out[(size_t)BB * LL * HH + (size_t)b * HH + n] =
        out[((size_t)b * LL + (sl - 1)) * HH + n];
}

extern "C" void kernel_launch(void* const* d_in, const int* in_sizes, int n_in,
                              void* d_out, int out_size, void* d_ws, size_t ws_size,
                              hipStream_t stream) {
    const float* x    = (const float*)d_in[0];
    const float* tds  = (const float*)d_in[1];
    const float* w_ih = (const float*)d_in[2];
    const float* w_hh = (const float*)d_in[3];
    const float* b_ih = (const float*)d_in[4];
    const float* b_hh = (const float*)d_in[5];
    const float* dw0  = (const float*)d_in[6];
    const float* db0  = (const float*)d_in[7];
    const float* dw1  = (const float*)d_in[8];
    const float* db1  = (const float*)d_in[9];
    const float* h0   = (const float*)d_in[10];
    const int* seq_lens = (const int*)d_in[11];
    float* out = (float*)d_out;
    f16* wsh = (f16*)d_ws;

    prep_kernel<<<(PREP_TOTAL + 255) / 256, 256, 0, stream>>>(dw0, dw1, w_ih, w_hh, h0, wsh);
    odegru_kernel<<<64, 512, 0, stream>>>(x, tds, b_ih, b_hh, db0, db1, h0, seq_lens, wsh, out);
    finalize_kernel<<<BB, HH, 0, stream>>>(seq_lens, out);
}